// Round 1
// baseline (177.039 us; speedup 1.0000x reference)
//
#include <hip/hip_runtime.h>
#include <math.h>

// FSQuantizer fused pipeline for MI355X.
// Shapes fixed by the reference: z (32,512,4096) f32, E=4, LEVELS={8,5,5,5}.
// Output: zhat (32,512,4096) f32, then commit_loss, then perplexity (flat).

namespace {
constexpr int Bv = 32, Cv = 512, Tv = 4096;
constexpr int Nv = Bv * Tv;                      // 131072 "rows" (b,t)
constexpr long long TOTv = (long long)Nv * Cv;   // 67108864 elements of z/zhat
constexpr int NTILES = Nv / 256;                 // 512 n-tiles of 256
constexpr int CSPLIT = 4;                        // c-splits in pass C
constexpr int CL = Cv / CSPLIT;                  // 128 c per block

// workspace layout (bytes)
constexpr size_t OFF_H   = 0;                                         // h: N*4 doubles (4 MiB)
constexpr size_t OFF_G   = OFF_H  + (size_t)Nv * 4 * sizeof(double);  // g: N*4 floats (2 MiB)
constexpr size_t OFF_BS  = OFF_G  + (size_t)Nv * 4 * sizeof(float);   // block stats: 512*10 doubles
constexpr size_t OFF_CST = OFF_BS + (size_t)NTILES * 10 * sizeof(double); // 32 doubles
constexpr size_t OFF_CNT = OFF_CST + 32 * sizeof(double);             // 1000 uint (pad 4096)
constexpr size_t OFF_CP  = OFF_CNT + 4096;                            // 512 doubles
constexpr size_t OFF_WD  = OFF_CP  + (size_t)NTILES * sizeof(double); // W_in as double: 2048
constexpr size_t OFF_WT  = OFF_WD  + 2048 * sizeof(double);           // W_out^T floats: 2048
}

// ---- kernel 0: precondition weights (W_in -> f64, W_out -> transposed [c][e]) ----
__global__ void fsq_k0(const float* __restrict__ W_in, const float* __restrict__ W_out,
                       double* __restrict__ winD, float* __restrict__ woutT)
{
    const int i = blockIdx.x * 256 + threadIdx.x;
    if (i < 2048) {
        winD[i] = (double)W_in[i];              // layout [c][e], same as input
        const int c = i >> 2, e = i & 3;
        woutT[i] = W_out[e * 512 + c];          // [c][e]
    }
}

// ---- kernel A: read z once; h (f64), g (f32), block stats ----
__global__ __launch_bounds__(256) void fsq_kA(
    const float* __restrict__ z, const double* __restrict__ winD,
    const float* __restrict__ woutT, const float* __restrict__ b_out,
    const float* __restrict__ b_in,
    double* __restrict__ h_ws, float* __restrict__ g_ws, double* __restrict__ bs_ws)
{
    __shared__ double red[256][10];
    const int tid = threadIdx.x;
    const int blk = blockIdx.x;                 // 0..511
    const int b = blk >> 4;                     // 16 tiles per b (T/256)
    const int tile = blk & 15;
    const int t = tile * 256 + tid;
    const float* zp = z + (size_t)b * Cv * Tv + t;

    double h0 = 0.0, h1 = 0.0, h2 = 0.0, h3 = 0.0;
    float g0 = 0.f, g1 = 0.f, g2 = 0.f, g3 = 0.f, zbp = 0.f, z2p = 0.f;
#pragma unroll 8
    for (int c = 0; c < Cv; ++c) {
        const float zv = zp[(size_t)c * Tv];    // coalesced: lane i -> t0+i
        const double zd = (double)zv;
        h0 = fma(zd, winD[c * 4 + 0], h0);
        h1 = fma(zd, winD[c * 4 + 1], h1);
        h2 = fma(zd, winD[c * 4 + 2], h2);
        h3 = fma(zd, winD[c * 4 + 3], h3);
        g0 = fmaf(zv, woutT[c * 4 + 0], g0);
        g1 = fmaf(zv, woutT[c * 4 + 1], g1);
        g2 = fmaf(zv, woutT[c * 4 + 2], g2);
        g3 = fmaf(zv, woutT[c * 4 + 3], g3);
        zbp = fmaf(zv, b_out[c], zbp);
        z2p = fmaf(zv, zv, z2p);
    }
    h0 += (double)b_in[0]; h1 += (double)b_in[1];
    h2 += (double)b_in[2]; h3 += (double)b_in[3];

    const int n = blk * 256 + tid;
    double* hp = h_ws + (size_t)n * 4;
    double2 hA; hA.x = h0; hA.y = h1;
    double2 hB; hB.x = h2; hB.y = h3;
    *(double2*)(hp)     = hA;
    *(double2*)(hp + 2) = hB;
    *(float4*)(g_ws + (size_t)n * 4) = make_float4(g0, g1, g2, g3);

    red[tid][0] = h0; red[tid][1] = h1; red[tid][2] = h2; red[tid][3] = h3;
    red[tid][4] = h0 * h0; red[tid][5] = h1 * h1; red[tid][6] = h2 * h2; red[tid][7] = h3 * h3;
    red[tid][8] = (double)z2p; red[tid][9] = (double)zbp;
    __syncthreads();
    for (int s = 128; s > 0; s >>= 1) {
        if (tid < s) {
#pragma unroll
            for (int k = 0; k < 10; ++k) red[tid][k] += red[tid + s][k];
        }
        __syncthreads();
    }
    if (tid == 0) {
#pragma unroll
        for (int k = 0; k < 10; ++k) bs_ws[blk * 10 + k] = red[0][k];
    }
}

// ---- kernel B: finalize BN stats, Gram matrix, zero histogram ----
__global__ __launch_bounds__(512) void fsq_kB(
    const float* __restrict__ gamma, const float* __restrict__ beta,
    const float* __restrict__ W_out, const float* __restrict__ b_out,
    const double* __restrict__ bs_ws, double* __restrict__ consts,
    unsigned* __restrict__ counts)
{
    __shared__ double buf[512 * 15];            // 60 KiB
    const int tid = threadIdx.x;
    // phase 1: reduce 512x10 block stats
#pragma unroll
    for (int k = 0; k < 10; ++k) buf[tid * 15 + k] = bs_ws[tid * 10 + k];
    __syncthreads();
    for (int s = 256; s > 0; s >>= 1) {
        if (tid < s) {
#pragma unroll
            for (int k = 0; k < 10; ++k) buf[tid * 15 + k] += buf[(tid + s) * 15 + k];
        }
        __syncthreads();
    }
    double Sh[4] = {0, 0, 0, 0}, Sq[4] = {0, 0, 0, 0}, SZ2 = 0, SZB = 0;
    if (tid == 0) {
        Sh[0] = buf[0]; Sh[1] = buf[1]; Sh[2] = buf[2]; Sh[3] = buf[3];
        Sq[0] = buf[4]; Sq[1] = buf[5]; Sq[2] = buf[6]; Sq[3] = buf[7];
        SZ2 = buf[8]; SZB = buf[9];
    }
    __syncthreads();
    // phase 2: Gram of W_out rows + v + s0 (c = tid, C = 512 exactly)
    {
        const int c = tid;
        const double w0 = W_out[c], w1 = W_out[512 + c], w2 = W_out[1024 + c], w3 = W_out[1536 + c];
        const double bb = b_out[c];
        double* r = buf + tid * 15;
        r[0] = w0 * w0; r[1] = w0 * w1; r[2] = w0 * w2; r[3] = w0 * w3;
        r[4] = w1 * w1; r[5] = w1 * w2; r[6] = w1 * w3;
        r[7] = w2 * w2; r[8] = w2 * w3; r[9] = w3 * w3;
        r[10] = w0 * bb; r[11] = w1 * bb; r[12] = w2 * bb; r[13] = w3 * bb; r[14] = bb * bb;
    }
    __syncthreads();
    for (int s = 256; s > 0; s >>= 1) {
        if (tid < s) {
#pragma unroll
            for (int k = 0; k < 15; ++k) buf[tid * 15 + k] += buf[(tid + s) * 15 + k];
        }
        __syncthreads();
    }
    if (tid == 0) {
        const double Ninv = 1.0 / (double)Nv;
#pragma unroll
        for (int e = 0; e < 4; ++e) {
            const double mu = Sh[e] * Ninv;
            const double var = Sq[e] * Ninv - mu * mu;      // biased, matches jnp.var
            const double sc = (double)gamma[e] / sqrt(var + 1e-5);
            consts[e] = sc;
            consts[4 + e] = (double)beta[e] - mu * sc;
        }
        // G (full 4x4 from 10 unique)
        consts[8 + 0]  = buf[0]; consts[8 + 1]  = buf[1]; consts[8 + 2]  = buf[2]; consts[8 + 3]  = buf[3];
        consts[8 + 4]  = buf[1]; consts[8 + 5]  = buf[4]; consts[8 + 6]  = buf[5]; consts[8 + 7]  = buf[6];
        consts[8 + 8]  = buf[2]; consts[8 + 9]  = buf[5]; consts[8 + 10] = buf[7]; consts[8 + 11] = buf[8];
        consts[8 + 12] = buf[3]; consts[8 + 13] = buf[6]; consts[8 + 14] = buf[8]; consts[8 + 15] = buf[9];
        consts[24] = buf[10]; consts[25] = buf[11]; consts[26] = buf[12]; consts[27] = buf[13]; // v[e]
        consts[28] = buf[14];                                   // s0
        consts[29] = SZ2; consts[30] = SZB;
        consts[31] = tan(0.5 / ((8.0 - 1.0) * (1.0 - 1e-3) / 2.0)); // shift for level-8 dim
    }
    for (int i = tid; i < 1000; i += 512) counts[i] = 0;
}

// ---- kernel C: quantize + histogram + commit partials + write zhat (write-only on HBM) ----
__global__ __launch_bounds__(256) void fsq_kC(
    const float* __restrict__ woutT, const float* __restrict__ b_out,
    const double* __restrict__ h_ws, const float* __restrict__ g_ws,
    const double* __restrict__ consts, unsigned* __restrict__ counts,
    double* __restrict__ cp_ws, float* __restrict__ out)
{
    __shared__ double red[256];
    const int tid = threadIdx.x;
    const int nt = blockIdx.x;                  // n-tile
    const int ys = blockIdx.y;                  // c-split
    const int n = nt * 256 + tid;

    const double sc0 = consts[0], sc1 = consts[1], sc2 = consts[2], sc3 = consts[3];
    const double bi0 = consts[4], bi1 = consts[5], bi2 = consts[6], bi3 = consts[7];
    const double shift0 = consts[31];

    const double* hp = h_ws + (size_t)n * 4;
    const double hn0 = fma(hp[0], sc0, bi0);
    const double hn1 = fma(hp[1], sc1, bi1);
    const double hn2 = fma(hp[2], sc2, bi2);
    const double hn3 = fma(hp[3], sc3, bi3);

    constexpr double hl0 = (8.0 - 1.0) * (1.0 - 1e-3) / 2.0;   // 3.4965
    constexpr double hl1 = (5.0 - 1.0) * (1.0 - 1e-3) / 2.0;   // 1.998
    const double r0 = rint(tanh(hn0 + shift0) * hl0 - 0.5);    // in [-4,3]
    const double r1 = rint(tanh(hn1) * hl1);                   // in [-2,2]
    const double r2 = rint(tanh(hn2) * hl1);
    const double r3 = rint(tanh(hn3) * hl1);
    const double zd0 = r0 * 0.25, zd1 = r1 * 0.5, zd2 = r2 * 0.5, zd3 = r3 * 0.5; // exact
    const float zn0 = (float)zd0, zn1 = (float)zd1, zn2 = (float)zd2, zn3 = (float)zd3;

    if (ys == 0) {
        const int code = ((int)r0 + 4) + ((int)r1 + 2) * 8 + ((int)r2 + 2) * 40 + ((int)r3 + 2) * 200;
        atomicAdd(&counts[code], 1u);
        const float4 gv = *(const float4*)(g_ws + (size_t)n * 4);
        const double cg = zd0 * (double)gv.x + zd1 * (double)gv.y
                        + zd2 * (double)gv.z + zd3 * (double)gv.w;
        const double znd[4] = {zd0, zd1, zd2, zd3};
        double q = consts[28] + 2.0 * (zd0 * consts[24] + zd1 * consts[25]
                                     + zd2 * consts[26] + zd3 * consts[27]);
#pragma unroll
        for (int e = 0; e < 4; ++e)
#pragma unroll
            for (int f = 0; f < 4; ++f)
                q = fma(znd[e] * znd[f], consts[8 + e * 4 + f], q);
        red[tid] = q - 2.0 * cg;    // per-n: ||zhat_row||^2 - 2 z.zhat (minus b_out pieces held in SZB)
        __syncthreads();
        for (int s = 128; s > 0; s >>= 1) {
            if (tid < s) red[tid] += red[tid + s];
            __syncthreads();
        }
        if (tid == 0) cp_ws[nt] = red[0];
    }

    // project out: write-only, coalesced over t
    const int c0 = ys * CL;
    const size_t base = (size_t)(n >> 12) * ((size_t)Cv * Tv) + (size_t)(n & (Tv - 1));
#pragma unroll 8
    for (int i = 0; i < CL; ++i) {
        const int c = c0 + i;
        float val = b_out[c];
        val = fmaf(zn0, woutT[c * 4 + 0], val);
        val = fmaf(zn1, woutT[c * 4 + 1], val);
        val = fmaf(zn2, woutT[c * 4 + 2], val);
        val = fmaf(zn3, woutT[c * 4 + 3], val);
        out[base + (size_t)c * Tv] = val;
    }
}

// ---- kernel D: finalize commit_loss + perplexity ----
__global__ __launch_bounds__(512) void fsq_kD(
    const double* __restrict__ cp_ws, const double* __restrict__ consts,
    const unsigned* __restrict__ counts, float* __restrict__ out, int out_size)
{
    __shared__ double rc[512];
    __shared__ double rp[512];
    const int tid = threadIdx.x;
    double c_ = cp_ws[tid];                     // exactly 512 partials
    double p_ = 0.0;
    for (int i = tid; i < 1000; i += 512) {
        const double em = (double)counts[i] / (double)Nv;
        p_ += em * log(em + 1e-10);
    }
    rc[tid] = c_; rp[tid] = p_;
    __syncthreads();
    for (int s = 256; s > 0; s >>= 1) {
        if (tid < s) { rc[tid] += rc[tid + s]; rp[tid] += rp[tid + s]; }
        __syncthreads();
    }
    if (tid == 0) {
        const double commit = (consts[29] - 2.0 * consts[30] + rc[0]) / (double)TOTv;
        out[out_size - 2] = (float)commit;
        out[out_size - 1] = (float)exp(-rp[0]);
    }
}

extern "C" void kernel_launch(void* const* d_in, const int* in_sizes, int n_in,
                              void* d_out, int out_size, void* d_ws, size_t ws_size,
                              hipStream_t stream) {
    const float* z     = (const float*)d_in[0];
    const float* W_in  = (const float*)d_in[1];
    const float* b_in  = (const float*)d_in[2];
    const float* gamma = (const float*)d_in[3];
    const float* beta  = (const float*)d_in[4];
    const float* W_out = (const float*)d_in[5];
    const float* b_out = (const float*)d_in[6];
    float* out = (float*)d_out;

    char* ws = (char*)d_ws;
    double*   h_ws   = (double*)(ws + OFF_H);
    float*    g_ws   = (float*)(ws + OFF_G);
    double*   bs_ws  = (double*)(ws + OFF_BS);
    double*   consts = (double*)(ws + OFF_CST);
    unsigned* counts = (unsigned*)(ws + OFF_CNT);
    double*   cp_ws  = (double*)(ws + OFF_CP);
    double*   winD   = (double*)(ws + OFF_WD);
    float*    woutT  = (float*)(ws + OFF_WT);

    fsq_k0<<<8, 256, 0, stream>>>(W_in, W_out, winD, woutT);
    fsq_kA<<<NTILES, 256, 0, stream>>>(z, winD, woutT, b_out, b_in, h_ws, g_ws, bs_ws);
    fsq_kB<<<1, 512, 0, stream>>>(gamma, beta, W_out, b_out, bs_ws, consts, counts);
    fsq_kC<<<dim3(NTILES, CSPLIT), 256, 0, stream>>>(woutT, b_out, h_ws, g_ws, consts,
                                                     counts, cp_ws, out);
    fsq_kD<<<1, 512, 0, stream>>>(cp_ws, consts, counts, out, out_size);
}